// Round 9
// baseline (182.698 us; speedup 1.0000x reference)
//
#include <hip/hip_runtime.h>

// Problem constants (fixed by reference: B=64, T=1024, D=256)
constexpr int Bn = 64;
constexpr int Tn = 1024;
constexpr int Dn = 256;

constexpr int TPB  = 256;        // 4 waves per block; block owns one t, wave owns K=64 slice
constexpr int NBLK = Tn;         // 1024 blocks -> 4 blocks/CU, 16 waves/CU of work
constexpr int NBIN = 64;         // partial-sum bins

using short8 = __attribute__((ext_vector_type(8))) short;   // 8 bf16 — MFMA A/B frag
using f32x16 = __attribute__((ext_vector_type(16))) float;  // MFMA 32x32 accumulator

__device__ __forceinline__ float dot4(const float4& a, const float4& b) {
    return a.x * b.x + a.y * b.y + a.z * b.z + a.w * b.w;
}

// fp32 -> bf16 bits, round-to-nearest-even
__device__ __forceinline__ unsigned int bfbits(float x) {
    unsigned int u = __builtin_bit_cast(unsigned int, x);
    return (u + 0x7FFFu + ((u >> 16) & 1u)) >> 16;
}
__device__ __forceinline__ unsigned int pack_bf2(float lo, float hi) {
    return bfbits(lo) | (bfbits(hi) << 16);
}

// One K=16 chunk of fragments, statically addressed (rule #20): 32 VGPRs.
struct Ch { float4 v0[2], v1[2], a0[2], a1[2]; };

__global__ __launch_bounds__(TPB, 3)   // 170 VGPR cap: fits 64 acc + 64 chunk + temps, no spill
void cmfm_main(const float* __restrict__ fv, const float* __restrict__ fa,
               const int* __restrict__ labels, float* __restrict__ acc)
{
    // Cross-wave norm exchange only (3 KB) — partial C never leaves registers.
    __shared__ float nv[4][Bn], na[4][Bn], nd[4][Bn];
    __shared__ float wred[3][4];

    const int lane = threadIdx.x & 63;
    const int wave = threadIdx.x >> 6;
    const int t    = blockIdx.x;           // block owns one timestep

    const int mrow = lane & 31;
    const int half = lane >> 5;

    // r8's verified fragment addressing + this wave's K-slice offset:
    // lane reads rows mrow / mrow+32, k-slice wave*64 + 8*half of each K=16 chunk.
    const size_t RS = (size_t)Tn * Dn;     // batch-row stride in floats
    const int koff  = wave * 64 + half * 8;
    const float* pv0 = fv + ((size_t)mrow * Tn + t) * Dn + koff;
    const float* pv1 = pv0 + 32 * RS;
    const float* pa0 = fa + ((size_t)mrow * Tn + t) * Dn + koff;
    const float* pa1 = pa0 + 32 * RS;

    f32x16 C00, C01, C10, C11;             // 64x64 tile, partial over this wave's K=64
    #pragma unroll
    for (int r = 0; r < 16; ++r) { C00[r] = 0.f; C01[r] = 0.f; C10[r] = 0.f; C11[r] = 0.f; }

    float sqv0 = 0.f, sqv1 = 0.f, sqa0 = 0.f, sqa1 = 0.f, dva0 = 0.f, dva1 = 0.f;

    #define LOADC(ch, OFF) do {                                              \
        ch.v0[0] = *reinterpret_cast<const float4*>(pv0 + (OFF));            \
        ch.v0[1] = *reinterpret_cast<const float4*>(pv0 + (OFF) + 4);        \
        ch.v1[0] = *reinterpret_cast<const float4*>(pv1 + (OFF));            \
        ch.v1[1] = *reinterpret_cast<const float4*>(pv1 + (OFF) + 4);        \
        ch.a0[0] = *reinterpret_cast<const float4*>(pa0 + (OFF));            \
        ch.a0[1] = *reinterpret_cast<const float4*>(pa0 + (OFF) + 4);        \
        ch.a1[0] = *reinterpret_cast<const float4*>(pa1 + (OFF));            \
        ch.a1[1] = *reinterpret_cast<const float4*>(pa1 + (OFF) + 4);        \
    } while (0)

    #define CONSUME(ch) do {                                                 \
        sqv0 += dot4(ch.v0[0], ch.v0[0]) + dot4(ch.v0[1], ch.v0[1]);         \
        sqv1 += dot4(ch.v1[0], ch.v1[0]) + dot4(ch.v1[1], ch.v1[1]);         \
        sqa0 += dot4(ch.a0[0], ch.a0[0]) + dot4(ch.a0[1], ch.a0[1]);         \
        sqa1 += dot4(ch.a1[0], ch.a1[0]) + dot4(ch.a1[1], ch.a1[1]);         \
        dva0 += dot4(ch.v0[0], ch.a0[0]) + dot4(ch.v0[1], ch.a0[1]);         \
        dva1 += dot4(ch.v1[0], ch.a1[0]) + dot4(ch.v1[1], ch.a1[1]);         \
        union { short8 s8; uint4 u4; } vf0, vf1, af0, af1;                   \
        vf0.u4.x = pack_bf2(ch.v0[0].x, ch.v0[0].y);                         \
        vf0.u4.y = pack_bf2(ch.v0[0].z, ch.v0[0].w);                         \
        vf0.u4.z = pack_bf2(ch.v0[1].x, ch.v0[1].y);                         \
        vf0.u4.w = pack_bf2(ch.v0[1].z, ch.v0[1].w);                         \
        vf1.u4.x = pack_bf2(ch.v1[0].x, ch.v1[0].y);                         \
        vf1.u4.y = pack_bf2(ch.v1[0].z, ch.v1[0].w);                         \
        vf1.u4.z = pack_bf2(ch.v1[1].x, ch.v1[1].y);                         \
        vf1.u4.w = pack_bf2(ch.v1[1].z, ch.v1[1].w);                         \
        af0.u4.x = pack_bf2(ch.a0[0].x, ch.a0[0].y);                         \
        af0.u4.y = pack_bf2(ch.a0[0].z, ch.a0[0].w);                         \
        af0.u4.z = pack_bf2(ch.a0[1].x, ch.a0[1].y);                         \
        af0.u4.w = pack_bf2(ch.a0[1].z, ch.a0[1].w);                         \
        af1.u4.x = pack_bf2(ch.a1[0].x, ch.a1[0].y);                         \
        af1.u4.y = pack_bf2(ch.a1[0].z, ch.a1[0].w);                         \
        af1.u4.z = pack_bf2(ch.a1[1].x, ch.a1[1].y);                         \
        af1.u4.w = pack_bf2(ch.a1[1].z, ch.a1[1].w);                         \
        C00 = __builtin_amdgcn_mfma_f32_32x32x16_bf16(vf0.s8, af0.s8, C00, 0, 0, 0); \
        C01 = __builtin_amdgcn_mfma_f32_32x32x16_bf16(vf0.s8, af1.s8, C01, 0, 0, 0); \
        C10 = __builtin_amdgcn_mfma_f32_32x32x16_bf16(vf1.s8, af0.s8, C10, 0, 0, 0); \
        C11 = __builtin_amdgcn_mfma_f32_32x32x16_bf16(vf1.s8, af1.s8, C11, 0, 0, 0); \
    } while (0)

    // 4 chunks (K=64), load-ahead-one with two named buffers; rolled backedge
    // caps scheduler hoisting at <=2 chunks (64 data VGPRs) -> no r4/r8 spill.
    Ch cA, cB;
    LOADC(cA, 0);
    #pragma unroll 1
    for (int c = 0; c < 4; c += 2) {
        LOADC(cB, (c + 1) * 16);           // in flight across CONSUME(cA)
        CONSUME(cA);
        if (c + 2 < 4) LOADC(cA, (c + 2) * 16);
        CONSUME(cB);
    }
    #undef LOADC
    #undef CONSUME

    // ---- partial norms over this wave's K-slice: combine lane-halves, post to LDS ----
    sqv0 += __shfl_xor(sqv0, 32);  sqv1 += __shfl_xor(sqv1, 32);
    sqa0 += __shfl_xor(sqa0, 32);  sqa1 += __shfl_xor(sqa1, 32);
    dva0 += __shfl_xor(dva0, 32);  dva1 += __shfl_xor(dva1, 32);
    if (half == 0) {
        nv[wave][mrow] = sqv0;  nv[wave][mrow + 32] = sqv1;
        na[wave][mrow] = sqa0;  na[wave][mrow + 32] = sqa1;
        nd[wave][mrow] = dva0;  nd[wave][mrow + 32] = dva1;
    }
    __syncthreads();                        // the ONLY barrier in the kernel

    // ---- full-K norms (sum the 4 wave partials) ----
    const float fv0 = nv[0][mrow]      + nv[1][mrow]      + nv[2][mrow]      + nv[3][mrow];
    const float fv1 = nv[0][mrow + 32] + nv[1][mrow + 32] + nv[2][mrow + 32] + nv[3][mrow + 32];
    const float fa0 = na[0][mrow]      + na[1][mrow]      + na[2][mrow]      + na[3][mrow];
    const float fa1 = na[0][mrow + 32] + na[1][mrow + 32] + na[2][mrow + 32] + na[3][mrow + 32];
    const float rv0 = 1.f / fmaxf(sqrtf(fv0), 1e-8f);   // V row mrow
    const float rv1 = 1.f / fmaxf(sqrtf(fv1), 1e-8f);   // V row mrow+32
    const float ra0 = 1.f / fmaxf(sqrtf(fa0), 1e-8f);   // A row mrow
    const float ra1 = 1.f / fmaxf(sqrtf(fa1), 1e-8f);   // A row mrow+32

    // ---- aligned-pair term: wave 0, lanes 0-31 only (each row exactly once) ----
    float pos = 0.f, neg = 0.f;
    if (wave == 0 && half == 0) {
        const float fd0 = nd[0][mrow]      + nd[1][mrow]      + nd[2][mrow]      + nd[3][mrow];
        const float fd1 = nd[0][mrow + 32] + nd[1][mrow + 32] + nd[2][mrow + 32] + nd[3][mrow + 32];
        const float c0 = fd0 * rv0 * ra0;
        const float c1 = fd1 * rv1 * ra1;
        if (labels[mrow] == 0)      pos += 1.f - c0; else neg += c0;   // d = 1-cos / cos
        if (labels[mrow + 32] == 0) pos += 1.f - c1; else neg += c1;
    }

    // ---- cross term: each wave reduces ITS partial C with full norms (linear in C) ----
    // C/D mapping (m74/m101, validated r1-r8): col = lane&31,
    // row ri = (reg&3) + 8*(reg>>2) + 4*(lane>>5)
    float od = 0.f;
    #define TILE(Cxx, RV, RA, EXCL) do {                                     \
        _Pragma("unroll")                                                    \
        for (int r = 0; r < 16; ++r) {                                       \
            const int ri = (r & 3) + 8 * (r >> 2) + 4 * half;                \
            const float rvi = __shfl(RV, ri);                                \
            float cc = Cxx[r];                                               \
            if (EXCL && ri == mrow) cc = 0.f;                                \
            od += rvi * (RA) * cc;                                           \
        }                                                                    \
    } while (0)
    TILE(C00, rv0, ra0, true);     // rows 0-31  x cols 0-31  (diagonal)
    TILE(C01, rv0, ra1, false);    // rows 0-31  x cols 32-63
    TILE(C10, rv1, ra0, false);    // rows 32-63 x cols 0-31
    TILE(C11, rv1, ra1, true);     // rows 32-63 x cols 32-63 (diagonal)
    #undef TILE

    // ---- block reduce (pos/neg nonzero only on wave 0) + 3 atomics ----
    #pragma unroll
    for (int off = 1; off < 64; off <<= 1) {
        pos += __shfl_xor(pos, off);
        neg += __shfl_xor(neg, off);
        od  += __shfl_xor(od, off);
    }
    if (lane == 0) { wred[0][wave] = pos; wred[1][wave] = neg; wred[2][wave] = od; }
    __syncthreads();
    if (threadIdx.x == 0) {
        float p = 0.f, n = 0.f, o = 0.f;
        #pragma unroll
        for (int w = 0; w < 4; ++w) { p += wred[0][w]; n += wred[1][w]; o += wred[2][w]; }
        float* bin = acc + (size_t)(t & (NBIN - 1)) * 4;
        atomicAdd(bin + 0, p);
        atomicAdd(bin + 1, n);
        atomicAdd(bin + 2, o);
    }
}

__global__ void cmfm_final(const int* __restrict__ labels, const float* __restrict__ acc,
                           float* __restrict__ out) {
    const int l = threadIdx.x;     // 64 threads = 64 bins = 64 labels
    float p = acc[l * 4 + 0];
    float n = acc[l * 4 + 1];
    float o = acc[l * 4 + 2];
    float npf = (labels[l] == 0) ? 1.f : 0.f;
    #pragma unroll
    for (int off = 1; off < 64; off <<= 1) {
        p += __shfl_xor(p, off);
        n += __shfl_xor(n, off);
        o += __shfl_xor(o, off);
        npf += __shfl_xor(npf, off);
    }
    if (l == 0) {
        const int np = (int)(npf + 0.5f);
        const float cnt_pos = (float)np * (float)Tn;
        const float cnt_neg = (float)(Bn - np) * (float)Tn + (float)Bn * (float)(Bn - 1);
        float loss = 0.f;
        if (np > 0) loss += 2.0f * p / cnt_pos;                  // ALPHA
        loss += (2.0f * n + 1.0f * o / (float)Tn) / cnt_neg;     // BETA, GAMMA
        out[0] = loss;
    }
}

extern "C" void kernel_launch(void* const* d_in, const int* in_sizes, int n_in,
                              void* d_out, int out_size, void* d_ws, size_t ws_size,
                              hipStream_t stream) {
    const float* fv     = (const float*)d_in[0];
    const float* fa     = (const float*)d_in[1];
    const int*   labels = (const int*)d_in[2];
    float* acc = (float*)d_ws;        // 64 bins x {pos, neg, cross, pad}
    float* out = (float*)d_out;

    hipMemsetAsync(acc, 0, NBIN * 4 * sizeof(float), stream);
    cmfm_main<<<NBLK, TPB, 0, stream>>>(fv, fa, labels, acc);
    cmfm_final<<<1, 64, 0, stream>>>(labels, acc, out);
}